// Round 10
// baseline (64.482 us; speedup 1.0000x reference)
//
#include <hip/hip_runtime.h>
#include <stdint.h>

#define N_T   3072
#define D_T   128
#define K_T   1536
#define FS_T  192
#define RES_T 1345
#define TOT_T (RES_T * FS_T)   // 258240
#define TINYF 1.17549435e-38f
#define NBLK  256
#define NTHR  384
#define WPB   6                // waves per block
#define NWAVE (NBLK * WPB)     // 1536
#define SLOT  32               // ints per 128B slot

// ---------------- relaxed agent-scope (LLC write-through) accessors ----------------
__device__ __forceinline__ void ast_d(double* p, double v) { __hip_atomic_store(p, v, __ATOMIC_RELAXED, __HIP_MEMORY_SCOPE_AGENT); }
__device__ __forceinline__ void ast_f(float* p, float v)   { __hip_atomic_store(p, v, __ATOMIC_RELAXED, __HIP_MEMORY_SCOPE_AGENT); }
__device__ __forceinline__ void ast_i(int* p, int v)       { __hip_atomic_store(p, v, __ATOMIC_RELAXED, __HIP_MEMORY_SCOPE_AGENT); }
__device__ __forceinline__ double ald_d(double* p) { return __hip_atomic_load(p, __ATOMIC_RELAXED, __HIP_MEMORY_SCOPE_AGENT); }
__device__ __forceinline__ float  ald_f(float* p)  { return __hip_atomic_load(p, __ATOMIC_RELAXED, __HIP_MEMORY_SCOPE_AGENT); }
__device__ __forceinline__ int    ald_i(int* p)    { return __hip_atomic_load(p, __ATOMIC_RELAXED, __HIP_MEMORY_SCOPE_AGENT); }

// ---------------- wave-level reductions (64 lanes, fixed order, deterministic) ----------------

__device__ __forceinline__ double wsumd(double v) {
  v += __shfl_xor(v, 1);  v += __shfl_xor(v, 2);  v += __shfl_xor(v, 4);
  v += __shfl_xor(v, 8);  v += __shfl_xor(v, 16); v += __shfl_xor(v, 32);
  return v;
}
__device__ __forceinline__ double wmaxd(double v) {
  v = fmax(v, __shfl_xor(v, 1));  v = fmax(v, __shfl_xor(v, 2));
  v = fmax(v, __shfl_xor(v, 4));  v = fmax(v, __shfl_xor(v, 8));
  v = fmax(v, __shfl_xor(v, 16)); v = fmax(v, __shfl_xor(v, 32));
  return v;
}
__device__ __forceinline__ float wsumf(float v) {
  v += __shfl_xor(v, 1);  v += __shfl_xor(v, 2);  v += __shfl_xor(v, 4);
  v += __shfl_xor(v, 8);  v += __shfl_xor(v, 16); v += __shfl_xor(v, 32);
  return v;
}
__device__ __forceinline__ float wmaxf(float v) {
  v = fmaxf(v, __shfl_xor(v, 1));  v = fmaxf(v, __shfl_xor(v, 2));
  v = fmaxf(v, __shfl_xor(v, 4));  v = fmaxf(v, __shfl_xor(v, 8));
  v = fmaxf(v, __shfl_xor(v, 16)); v = fmaxf(v, __shfl_xor(v, 32));
  return v;
}
__device__ __forceinline__ int wsumi(int v) {
  v += __shfl_xor(v, 1);  v += __shfl_xor(v, 2);  v += __shfl_xor(v, 4);
  v += __shfl_xor(v, 8);  v += __shfl_xor(v, 16); v += __shfl_xor(v, 32);
  return v;
}

// ---------------- fence-free, fully distributed grid barrier ----------------
// Layout (zeroed per launch): arrive slots = sync[(b*NBLK + blk)*SLOT];
// done slots = sync[ARR_SZ + (b*NBLK + blk)*SLOT]. Every word sits on its own
// 128B line -> no shared-line congestion on arrival, aggregation, or broadcast.
// Block 0 wave 0 aggregates and fans out 256 private done stores.
// Safe: 256 blocks <= 256 CUs -> all co-resident.
#define ARR_SZ (4 * NBLK * SLOT)
__device__ __forceinline__ void grid_barrier(int* sync, int b) {
  asm volatile("s_waitcnt vmcnt(0)" ::: "memory");   // my LLC stores complete
  __syncthreads();                                   // all waves of block drained
  int* arrive = sync + b * NBLK * SLOT;
  int* done   = sync + ARR_SZ + b * NBLK * SLOT;
  if (blockIdx.x == 0) {
    if (threadIdx.x < 64) {
      int lane = threadIdx.x;
      if (lane == 0) ast_i(&arrive[0], 1);
      for (;;) {
        int v0 = ald_i(&arrive[lane * SLOT]);
        int v1 = ald_i(&arrive[(lane + 64) * SLOT]);
        int v2 = ald_i(&arrive[(lane + 128) * SLOT]);
        int v3 = ald_i(&arrive[(lane + 192) * SLOT]);
        if (__all((v0 & v1 & v2 & v3) != 0)) break;
        __builtin_amdgcn_s_sleep(1);
      }
      // fan-out: 4 private done stores per lane, all parallel, fire-and-forget
      ast_i(&done[lane * SLOT], 1);
      ast_i(&done[(lane + 64) * SLOT], 1);
      ast_i(&done[(lane + 128) * SLOT], 1);
      ast_i(&done[(lane + 192) * SLOT], 1);
    }
  } else {
    if (threadIdx.x == 0) {
      ast_i(&arrive[blockIdx.x * SLOT], 1);
      while (ald_i(&done[blockIdx.x * SLOT]) == 0) __builtin_amdgcn_s_sleep(2);
    }
  }
  asm volatile("" ::: "memory");                     // no reordering across the poll
  __syncthreads();                                   // release the other waves
}

// ---------------- threefry-2x32 (exact JAX bits, partitionable layout) ----------------

__device__ __forceinline__ uint32_t rotl32(uint32_t x, uint32_t r) {
  return (x << r) | (x >> (32u - r));
}

__device__ __forceinline__ void threefry2x32(uint32_t k0, uint32_t k1,
                                             uint32_t x0, uint32_t x1,
                                             uint32_t& o0, uint32_t& o1) {
  uint32_t ks0 = k0, ks1 = k1, ks2 = k0 ^ k1 ^ 0x1BD11BDAu;
  x0 += ks0; x1 += ks1;
  x0 += x1; x1 = rotl32(x1, 13); x1 ^= x0;
  x0 += x1; x1 = rotl32(x1, 15); x1 ^= x0;
  x0 += x1; x1 = rotl32(x1, 26); x1 ^= x0;
  x0 += x1; x1 = rotl32(x1, 6);  x1 ^= x0;
  x0 += ks1; x1 += ks2 + 1u;
  x0 += x1; x1 = rotl32(x1, 17); x1 ^= x0;
  x0 += x1; x1 = rotl32(x1, 29); x1 ^= x0;
  x0 += x1; x1 = rotl32(x1, 16); x1 ^= x0;
  x0 += x1; x1 = rotl32(x1, 24); x1 ^= x0;
  x0 += ks2; x1 += ks0 + 2u;
  x0 += x1; x1 = rotl32(x1, 13); x1 ^= x0;
  x0 += x1; x1 = rotl32(x1, 15); x1 ^= x0;
  x0 += x1; x1 = rotl32(x1, 26); x1 ^= x0;
  x0 += x1; x1 = rotl32(x1, 6);  x1 ^= x0;
  x0 += ks0; x1 += ks1 + 3u;
  x0 += x1; x1 = rotl32(x1, 17); x1 ^= x0;
  x0 += x1; x1 = rotl32(x1, 29); x1 ^= x0;
  x0 += x1; x1 = rotl32(x1, 16); x1 ^= x0;
  x0 += x1; x1 = rotl32(x1, 24); x1 ^= x0;
  x0 += ks1; x1 += ks2 + 4u;
  x0 += x1; x1 = rotl32(x1, 13); x1 ^= x0;
  x0 += x1; x1 = rotl32(x1, 15); x1 ^= x0;
  x0 += x1; x1 = rotl32(x1, 26); x1 ^= x0;
  x0 += x1; x1 = rotl32(x1, 6);  x1 ^= x0;
  x0 += ks2; x1 += ks0 + 5u;
  o0 = x0; o1 = x1;
}

__device__ __forceinline__ float jax_gumbel(uint32_t i) {
  uint32_t o0, o1;
  threefry2x32(0u, 777u, 0u, i, o0, o1);
  uint32_t bits = o0 ^ o1;
  uint32_t fb = (bits >> 9) | 0x3F800000u;
  float u = __uint_as_float(fb) - 1.0f;    // [0,1)
  float uu = fmaxf(TINYF, u + TINYF);
  return -logf(-logf(uu));
}

// ---------------- fused pipeline, one launch, 4 distributed grid barriers ----------------
__global__ __launch_bounds__(NTHR, 2) void fused(
    const float* __restrict__ x, const float* __restrict__ sw,
    const float* __restrict__ att, const int* __restrict__ epoch_p,
    float* __restrict__ out, int* __restrict__ sync,
    double* __restrict__ scores, double* __restrict__ ball,
    double* __restrict__ logits, int* __restrict__ perm,
    float* __restrict__ sm_sort) {
  __shared__ double sc_lds[N_T];     // 24 KB, phase-2 score cache
  const int tid = threadIdx.x;
  const int lane = tid & 63;
  const int gw = blockIdx.x * WPB + (tid >> 6);   // 0..NWAVE-1

  // ---- phase 1: scores[i] = x[i].sw ; ball[i] = x[i].wb  (f64, wave per row)
  for (int i = gw; i < N_T; i += NWAVE) {
    double xv0 = (double)x[i * D_T + lane];
    double xv1 = (double)x[i * D_T + 64 + lane];
    double ps = xv0 * (double)sw[lane] + xv1 * (double)sw[64 + lane];
    double pb = xv0 * (double)att[D_T + lane] + xv1 * (double)att[D_T + 64 + lane];
    ps = wsumd(ps);
    pb = wsumd(pb);
    if (lane == 0) { ast_d(&scores[i], ps); ast_d(&ball[i], pb); }
  }
  grid_barrier(sync, 0);

  // ---- phase 2: stage scores to LDS, rank each element; if rank<K, perm[rank]=i
  for (int j = tid; j < N_T; j += NTHR) sc_lds[j] = ald_d(&scores[j]);
  __syncthreads();
  for (int i = gw; i < N_T; i += NWAVE) {
    double si = sc_lds[i];
    int cnt = 0;
#pragma unroll 8
    for (int j = lane; j < N_T; j += 64) {
      double sj = sc_lds[j];
      cnt += ((sj > si) || (sj == si && j < i)) ? 1 : 0;
    }
    cnt = wsumi(cnt);
    if (lane == 0 && cnt < K_T) ast_i(&perm[cnt], i);
  }
  grid_barrier(sync, 1);

  // ---- phase 3: per-row softmax + gk + stable rank (one wave per row)
  // Block 0 excluded so the aggregator is already polling when workers finish.
  if (gw >= WPB && gw < WPB + RES_T) {
    int r = gw - WPB;
    int pr  = ald_i(&perm[r]);
    int pd0 = ald_i(&perm[r + lane]);
    int pd1 = ald_i(&perm[r + 64 + lane]);
    int pd2 = ald_i(&perm[r + 128 + lane]);

    double s0 = ald_d(&ball[pd0]), s1 = ald_d(&ball[pd1]), s2 = ald_d(&ball[pd2]);
    double mx = wmaxd(fmax(s0, fmax(s1, s2)));
    double e0 = exp(s0 - mx), e1 = exp(s1 - mx), e2 = exp(s2 - mx);
    double ssum = wsumd(e0 + e1 + e2);

    float xa = x[pr * D_T + lane];        // dims lane
    float xb = x[pr * D_T + 64 + lane];   // dims 64+lane
    const float4* r0 = (const float4*)(x + (size_t)pd0 * D_T);
    const float4* r1 = (const float4*)(x + (size_t)pd1 * D_T);
    const float4* r2 = (const float4*)(x + (size_t)pd2 * D_T);
    double sq0 = 0.0, sq1 = 0.0, sq2 = 0.0;
#pragma unroll 4
    for (int tt = 0; tt < 32; ++tt) {
      float4 v0 = r0[tt], v1 = r1[tt], v2 = r2[tt];
      float src = (tt < 16) ? xa : xb;
      int base = (tt * 4) & 63;
      float u0 = __shfl(src, base);
      float u1 = __shfl(src, base + 1);
      float u2 = __shfl(src, base + 2);
      float u3 = __shfl(src, base + 3);
      float d;
      d = u0 - v0.x; sq0 += (double)d * (double)d;
      d = u1 - v0.y; sq0 += (double)d * (double)d;
      d = u2 - v0.z; sq0 += (double)d * (double)d;
      d = u3 - v0.w; sq0 += (double)d * (double)d;
      d = u0 - v1.x; sq1 += (double)d * (double)d;
      d = u1 - v1.y; sq1 += (double)d * (double)d;
      d = u2 - v1.z; sq1 += (double)d * (double)d;
      d = u3 - v1.w; sq1 += (double)d * (double)d;
      d = u0 - v2.x; sq2 += (double)d * (double)d;
      d = u1 - v2.y; sq2 += (double)d * (double)d;
      d = u2 - v2.z; sq2 += (double)d * (double)d;
      d = u3 - v2.w; sq2 += (double)d * (double)d;
    }
    double g0v = exp(-sqrt(fmax(sq0, 1e-24)) * 0.5) - 1e-5;
    double g1v = exp(-sqrt(fmax(sq1, 1e-24)) * 0.5) - 1e-5;
    double g2v = exp(-sqrt(fmax(sq2, 1e-24)) * 0.5) - 1e-5;

    // stable descending rank among the row's 192 values (f index tie-break)
    int rk0 = 0, rk1 = 0, rk2 = 0;
#pragma unroll 4
    for (int j = 0; j < 64; ++j) {
      double h0 = __shfl(g0v, j), h1 = __shfl(g1v, j), h2 = __shfl(g2v, j);
      rk0 += ((h0 > g0v) || (h0 == g0v && j < lane)) ? 1 : 0;
      rk0 += (h1 > g0v) ? 1 : 0;
      rk0 += (h2 > g0v) ? 1 : 0;
      rk1 += ((h0 > g1v) || (h0 == g1v)) ? 1 : 0;
      rk1 += ((h1 > g1v) || (h1 == g1v && j < lane)) ? 1 : 0;
      rk1 += (h2 > g1v) ? 1 : 0;
      rk2 += ((h0 > g2v) || (h0 == g2v)) ? 1 : 0;
      rk2 += ((h1 > g2v) || (h1 == g2v)) ? 1 : 0;
      rk2 += ((h2 > g2v) || (h2 == g2v && j < lane)) ? 1 : 0;
    }
    size_t rb = (size_t)r * FS_T;
    double inv = 1.0 / ssum;
    ast_f(&out[rb + rk0], (float)g0v);  ast_f(&sm_sort[rb + rk0], (float)(e0 * inv));
    ast_f(&out[rb + rk1], (float)g1v);  ast_f(&sm_sort[rb + rk1], (float)(e1 * inv));
    ast_f(&out[rb + rk2], (float)g2v);  ast_f(&sm_sort[rb + rk2], (float)(e2 * inv));
  }
  grid_barrier(sync, 2);

  // ---- phase 4: logits[c] = sum_r sm_sort[r][c]  (wave per column; block 0 excluded)
  if (gw >= WPB && gw < WPB + FS_T) {
    int c = gw - WPB;
    double s = 0.0;
    for (int j = lane; j < RES_T; j += 64) s += (double)ald_f(&sm_sort[(size_t)j * FS_T + c]);
    s = wsumd(s);
    if (lane == 0) ast_d(&logits[c], s);
  }
  grid_barrier(sync, 3);

  // ---- phase 5: gumbel softmax * gk  (wave per row)
  if (gw < RES_T) {
    int r = gw;
    int i0 = r * FS_T + lane, i1 = i0 + 64, i2 = i0 + 128;
    float gk0 = ald_f(&out[i0]), gk1 = ald_f(&out[i1]), gk2 = ald_f(&out[i2]);
    float gb0 = jax_gumbel((uint32_t)i0);
    float gb1 = jax_gumbel((uint32_t)i1);
    float gb2 = jax_gumbel((uint32_t)i2);
    double l0 = ald_d(&logits[lane]);
    double l1 = ald_d(&logits[64 + lane]);
    double l2 = ald_d(&logits[128 + lane]);

    int ei = epoch_p[0];
    double epoch;
    if (ei >= 0 && ei <= 100000) epoch = (double)ei;
    else {
      float ef = __int_as_float(ei);
      epoch = (ef >= 0.0f && ef <= 100000.0f) ? (double)ef : 50.0;
    }
    double invtau = 0.1 * exp(0.04605170185988091 * epoch);   // 1/tau0

    float z0 = (lane == 0) ? -INFINITY : (float)(((double)gb0 + l0) * invtau);
    float z1 = (float)(((double)gb1 + l1) * invtau);
    float z2 = (float)(((double)gb2 + l2) * invtau);
    float m = wmaxf(fmaxf(z0, fmaxf(z1, z2)));
    float e0 = (lane == 0) ? 0.0f : expf(z0 - m);
    float e1 = expf(z1 - m);
    float e2 = expf(z2 - m);
    float ssum = wsumf(e0 + e1 + e2);
    float invs = 1.0f / ssum;
    out[i0] = gk0 * (e0 * invs);
    out[i1] = gk1 * (e1 * invs);
    out[i2] = gk2 * (e2 * invs);
  }
}

// ---------------- launcher ----------------
extern "C" void kernel_launch(void* const* d_in, const int* in_sizes, int n_in,
                              void* d_out, int out_size, void* d_ws, size_t ws_size,
                              hipStream_t stream) {
  const float* x   = (const float*)d_in[0];
  // d_in[1] = edge_index (unused by the reference)
  const float* sw  = (const float*)d_in[2];
  // d_in[3] = score_b (order-preserving constant shift; unused)
  const float* att = (const float*)d_in[4];
  const int* epoch = (const int*)d_in[5];
  float* out = (float*)d_out;

  char* ws = (char*)d_ws;
  size_t sync_bytes = (size_t)2 * ARR_SZ * sizeof(int);   // arrive + done = 256 KB
  int*    sync    = (int*)ws;
  double* scores  = (double*)(ws + sync_bytes);  // 3072
  double* ball    = scores + N_T;                // 3072
  double* logits  = ball + N_T;                  // 192
  int*    perm    = (int*)(logits + FS_T);       // 1536
  float*  sm_sort = (float*)(perm + K_T);        // 258240   (~1.35 MB total)

  (void)hipMemsetAsync(sync, 0, sync_bytes, stream);   // reset barrier state every launch
  fused<<<NBLK, NTHR, 0, stream>>>(x, sw, att, epoch, out, sync,
                                   scores, ball, logits, perm, sm_sort);
}